// Round 15
// baseline (1012.148 us; speedup 1.0000x reference)
//
#include <hip/hip_runtime.h>
#include <math.h>
#include <stdint.h>

#define NN 100000
#define NE 1600000
#define IN_DIM 128
#define HID 64
#define EDIM 16
#define NEG_SLOPE 0.2f

// ws layout (float offsets)
#define OFF_H    0          // NN*4
#define OFF_HS   400000     // NN
#define OFF_HD   500000     // NN
#define OFF_DEN  600000     // NN
#define OFF_XG   700000     // NN*4
#define OFF_IMG  2800000    // 19*256 u32

typedef __attribute__((ext_vector_type(8))) short bf16x8;
typedef __attribute__((ext_vector_type(4))) float f32x4;
typedef __attribute__((ext_vector_type(2))) float f32x2;
typedef __attribute__((ext_vector_type(2))) __bf16 bf16x2;
typedef __attribute__((ext_vector_type(2))) short s16x2;

#define MFMA16(A, B, C) __builtin_amdgcn_mfma_f32_16x16x32_bf16((A), (B), (C), 0, 0, 0)

__device__ inline bf16x8 as_bf(uint4 x) { union { uint4 a; bf16x8 b; } u; u.a = x; return u.b; }
__device__ inline f32x4 as_f4(uint4 x) { union { uint4 a; f32x4 f; } u; u.a = x; return u.f; }

// packed f32x2 -> bf16x2 via LLVM fptrunc (validated r10; lowers to v_cvt_pk_bf16_f32)
__device__ inline uint32_t pk2(float lo, float hi) {
    f32x2 v; v.x = lo; v.y = hi;
    bf16x2 b = __builtin_convertvector(v, bf16x2);
    union { bf16x2 b; uint32_t u; } uu; uu.b = b; return uu.u;
}

// convert + packed relu (validated r12): bf16 sign-magnitude => smax(i16,0) == relu
__device__ inline uint32_t pk2r(float lo, float hi) {
    f32x2 v; v.x = lo; v.y = hi;
    bf16x2 b = __builtin_convertvector(v, bf16x2);
    union { bf16x2 b; s16x2 s; uint32_t u; } uu; uu.b = b;
    s16x2 z = {0, 0};
    uu.s = __builtin_elementwise_max(uu.s, z);
    return uu.u;
}

// prep-side RNE pack (cold path)
__device__ inline uint16_t f2bf_rne(float f) {
    uint32_t x = __float_as_uint(f);
    uint32_t r = x + 0x7FFFu + ((x >> 16) & 1u);
    return (uint16_t)(r >> 16);
}
__device__ inline uint32_t pk2c(float lo, float hi) {
    return (uint32_t)f2bf_rne(lo) | ((uint32_t)f2bf_rne(hi) << 16);
}

// ---------------- GAT conv ----------------
__global__ void node_kernel(const float* __restrict__ x, const float* __restrict__ Wg,
                            const float* __restrict__ a_src, const float* __restrict__ a_dst,
                            float* __restrict__ h, float* __restrict__ hs,
                            float* __restrict__ hd, float* __restrict__ den,
                            float* __restrict__ xg) {
    int i = blockIdx.x * blockDim.x + threadIdx.x;
    if (i >= NN) return;
    float acc0 = 0.f, acc1 = 0.f, acc2 = 0.f, acc3 = 0.f;
    const float* xr = x + (size_t)i * IN_DIM;
#pragma unroll
    for (int d = 0; d < IN_DIM; d += 4) {
        float4 xv = *(const float4*)(xr + d);
        acc0 = fmaf(xv.x, Wg[(d + 0) * 4 + 0], acc0);
        acc1 = fmaf(xv.x, Wg[(d + 0) * 4 + 1], acc1);
        acc2 = fmaf(xv.x, Wg[(d + 0) * 4 + 2], acc2);
        acc3 = fmaf(xv.x, Wg[(d + 0) * 4 + 3], acc3);
        acc0 = fmaf(xv.y, Wg[(d + 1) * 4 + 0], acc0);
        acc1 = fmaf(xv.y, Wg[(d + 1) * 4 + 1], acc1);
        acc2 = fmaf(xv.y, Wg[(d + 1) * 4 + 2], acc2);
        acc3 = fmaf(xv.y, Wg[(d + 1) * 4 + 3], acc3);
        acc0 = fmaf(xv.z, Wg[(d + 2) * 4 + 0], acc0);
        acc1 = fmaf(xv.z, Wg[(d + 2) * 4 + 1], acc1);
        acc2 = fmaf(xv.z, Wg[(d + 2) * 4 + 2], acc2);
        acc3 = fmaf(xv.z, Wg[(d + 2) * 4 + 3], acc3);
        acc0 = fmaf(xv.w, Wg[(d + 3) * 4 + 0], acc0);
        acc1 = fmaf(xv.w, Wg[(d + 3) * 4 + 1], acc1);
        acc2 = fmaf(xv.w, Wg[(d + 3) * 4 + 2], acc2);
        acc3 = fmaf(xv.w, Wg[(d + 3) * 4 + 3], acc3);
    }
    *(float4*)(h + (size_t)i * 4) = make_float4(acc0, acc1, acc2, acc3);
    hs[i] = acc0 * a_src[0] + acc1 * a_src[1] + acc2 * a_src[2] + acc3 * a_src[3];
    hd[i] = acc0 * a_dst[0] + acc1 * a_dst[1] + acc2 * a_dst[2] + acc3 * a_dst[3];
    den[i] = 0.f;
    *(float4*)(xg + (size_t)i * 4) = make_float4(0.f, 0.f, 0.f, 0.f);
}

// real edges, 2 per thread (int2 coalesced index loads); self-loops in div_kernel
__global__ __launch_bounds__(256) void edge_kernel(
    const int* __restrict__ ei, const float* __restrict__ hs,
    const float* __restrict__ hd, const float* __restrict__ h,
    float* __restrict__ den, float* __restrict__ xg) {
    int t = blockIdx.x * blockDim.x + threadIdx.x;
    int e = 2 * t;
    if (e >= NE) return;
    int2 rr = *(const int2*)(ei + e);
    int2 cc = *(const int2*)(ei + NE + e);
    float v0 = hs[rr.x] + hd[cc.x];
    float v1 = hs[rr.y] + hd[cc.y];
    v0 = (v0 >= 0.f) ? v0 : NEG_SLOPE * v0;
    v1 = (v1 >= 0.f) ? v1 : NEG_SLOPE * v1;
    float p0 = __expf(v0), p1 = __expf(v1);
    float4 h0 = *(const float4*)(h + (size_t)rr.x * 4);
    float4 h1 = *(const float4*)(h + (size_t)rr.y * 4);
    atomicAdd(&den[cc.x], p0);
    atomicAdd(&xg[4 * cc.x + 0], p0 * h0.x);
    atomicAdd(&xg[4 * cc.x + 1], p0 * h0.y);
    atomicAdd(&xg[4 * cc.x + 2], p0 * h0.z);
    atomicAdd(&xg[4 * cc.x + 3], p0 * h0.w);
    atomicAdd(&den[cc.y], p1);
    atomicAdd(&xg[4 * cc.y + 0], p1 * h1.x);
    atomicAdd(&xg[4 * cc.y + 1], p1 * h1.y);
    atomicAdd(&xg[4 * cc.y + 2], p1 * h1.z);
    atomicAdd(&xg[4 * cc.y + 3], p1 * h1.w);
}

// self-loop contribution + normalization + bias
__global__ void div_kernel(const float* __restrict__ hs, const float* __restrict__ hd,
                           const float* __restrict__ h, float* __restrict__ xg,
                           const float* __restrict__ den, const float* __restrict__ b_gat) {
    int i = blockIdx.x * blockDim.x + threadIdx.x;
    if (i >= NN) return;
    float v = hs[i] + hd[i];
    v = (v >= 0.f) ? v : NEG_SLOPE * v;
    float pe = __expf(v);
    float4 hv = *(const float4*)(h + (size_t)i * 4);
    float inv = 1.0f / (den[i] + pe);
    float4 n = *(const float4*)(xg + (size_t)i * 4);
    *(float4*)(xg + (size_t)i * 4) =
        make_float4(fmaf(fmaf(pe, hv.x, n.x), inv, b_gat[0]),
                    fmaf(fmaf(pe, hv.y, n.y), inv, b_gat[1]),
                    fmaf(fmaf(pe, hv.z, n.z), inv, b_gat[2]),
                    fmaf(fmaf(pe, hv.w, n.w), inv, b_gat[3]));
}

// ---------------- fragment image prep (PERMUTED layout, validated r8-r14) ----------------
// u(q,g,r) = 32*(q&1) + 8*g + 4*(q>>1) + r; D-slot order == next layer's B k-order.
// Layer-1 B per lane g: j=0..3 -> y[4g+j]; j=4,5 -> f[2g],f[2g+1];
// j=6 (g==0 only) -> bias-one; j=7 -> zero.
__global__ void prep_kernel(const float* __restrict__ W1, const float* __restrict__ b1,
                            const float* __restrict__ W2, const float* __restrict__ b2,
                            const float* __restrict__ W3, const float* __restrict__ b3,
                            uint32_t* __restrict__ img) {
    int l = threadIdx.x;
    if (l >= 64) return;
    int e = l & 15, g = l >> 4;
    int er = e & 3, eq = e >> 2;
    for (int q = 0; q < 4; ++q) {
        int u = 32 * (q & 1) + 8 * eq + 4 * (q >> 1) + er;
        img[q * 256 + l * 4 + 0] = pk2c(W1[(8 + 4 * g + 0) * 64 + u], W1[(8 + 4 * g + 1) * 64 + u]);
        img[q * 256 + l * 4 + 1] = pk2c(W1[(8 + 4 * g + 2) * 64 + u], W1[(8 + 4 * g + 3) * 64 + u]);
        img[q * 256 + l * 4 + 2] = pk2c(W1[(2 * g + 0) * 64 + u], W1[(2 * g + 1) * 64 + u]);
        img[q * 256 + l * 4 + 3] = pk2c((g == 0) ? b1[u] : 0.f, 0.f);
    }
    for (int t = 0; t < 2; ++t)
        for (int q = 0; q < 4; ++q) {
            int u = 32 * (q & 1) + 8 * eq + 4 * (q >> 1) + er;
            for (int j2 = 0; j2 < 4; ++j2) {
                int k0 = 32 * t + 8 * g + 2 * j2;
                img[(4 + t * 4 + q) * 256 + l * 4 + j2] =
                    pk2c(W2[k0 * 64 + u], W2[(k0 + 1) * 64 + u]);
            }
        }
    for (int t = 0; t < 2; ++t)
        for (int j2 = 0; j2 < 4; ++j2) {
            int k0 = 32 * t + 8 * g + 2 * j2;
            img[(12 + t) * 256 + l * 4 + j2] =
                pk2c(W3[k0 * 16 + e], W3[(k0 + 1) * 16 + e]);
        }
    for (int q = 0; q < 4; ++q)
        for (int r = 0; r < 4; ++r)
            img[(14 + q) * 256 + l * 4 + r] =
                __float_as_uint(b2[32 * (q & 1) + 8 * g + 4 * (q >> 1) + r]);
    for (int r = 0; r < 4; ++r)
        img[18 * 256 + l * 4 + r] = __float_as_uint(b3[4 * g + r]);
}

// ---------------- RK4 edge MLP (r15): L2/L3 chain-split (independent MFMAs) ----------------
__global__ __launch_bounds__(256, 4) void rk4_kernel(
    const int* __restrict__ ei, const float* __restrict__ ea,
    const float* __restrict__ xg, const uint32_t* __restrict__ img,
    float* __restrict__ out) {
    const int tid = threadIdx.x;
    const int w = tid >> 6, l = tid & 63;
    const int e = l & 15, g = l >> 4;
    const int edge = blockIdx.x * 64 + w * 16 + e;

    uint4 F[19];
#pragma unroll
    for (int i = 0; i < 19; ++i) F[i] = *(const uint4*)(img + i * 256 + l * 4);

    const bf16x8 W1f0 = as_bf(F[0]), W1f1 = as_bf(F[1]), W1f2 = as_bf(F[2]), W1f3 = as_bf(F[3]);
    const bf16x8 W2f00 = as_bf(F[4]), W2f01 = as_bf(F[5]), W2f02 = as_bf(F[6]), W2f03 = as_bf(F[7]);
    const bf16x8 W2f10 = as_bf(F[8]), W2f11 = as_bf(F[9]), W2f12 = as_bf(F[10]), W2f13 = as_bf(F[11]);
    const bf16x8 W3f0 = as_bf(F[12]), W3f1 = as_bf(F[13]);
    const f32x4 b2f0 = as_f4(F[14]), b2f1 = as_f4(F[15]), b2f2 = as_f4(F[16]), b2f3 = as_f4(F[17]);
    const f32x4 b3f = as_f4(F[18]);

    uint32_t Stf, Stb;
    {
        int idx = (g < 2) ? ei[edge] : ei[NE + edge];
        const float2 fv = *(const float2*)(xg + (size_t)idx * 4 + ((2 * g) & 3));
        Stf = pk2(fv.x, fv.y);
        Stb = (g == 0) ? 0x00003F80u : 0u;  // bf16(1.0) at k=6
    }

    float4 y4 = *(const float4*)(ea + (size_t)edge * 16 + 4 * g);
    float yv0 = y4.x, yv1 = y4.y, yv2 = y4.z, yv3 = y4.w;

    const f32x4 zero4 = {0.f, 0.f, 0.f, 0.f};
    const float dt6 = 0.125f / 6.0f;

    auto rhs = [&](float a0, float a1, float a2, float a3) -> f32x4 {
        uint4 bb;
        bb.x = pk2(a0, a1); bb.y = pk2(a2, a3); bb.z = Stf; bb.w = Stb;
        bf16x8 B1 = as_bf(bb);
        __builtin_amdgcn_s_setprio(1);
        f32x4 h0 = MFMA16(W1f0, B1, zero4);
        f32x4 h1 = MFMA16(W1f1, B1, zero4);
        f32x4 h2 = MFMA16(W1f2, B1, zero4);
        f32x4 h3 = MFMA16(W1f3, B1, zero4);
        uint4 q20, q21;
        q20.x = pk2r(h0[0], h0[1]);
        q20.y = pk2r(h0[2], h0[3]);
        q20.z = pk2r(h2[0], h2[1]);
        q20.w = pk2r(h2[2], h2[3]);
        q21.x = pk2r(h1[0], h1[1]);
        q21.y = pk2r(h1[2], h1[3]);
        q21.z = pk2r(h3[0], h3[1]);
        q21.w = pk2r(h3[2], h3[3]);
        bf16x8 B20 = as_bf(q20), B21 = as_bf(q21);
        // L2: independent partial accumulators (chain depth 1, not 2); merge in pk
        f32x4 p0 = MFMA16(W2f00, B20, b2f0); f32x4 p0b = MFMA16(W2f10, B21, zero4);
        f32x4 p1 = MFMA16(W2f01, B20, b2f1); f32x4 p1b = MFMA16(W2f11, B21, zero4);
        f32x4 p2 = MFMA16(W2f02, B20, b2f2); f32x4 p2b = MFMA16(W2f12, B21, zero4);
        f32x4 p3 = MFMA16(W2f03, B20, b2f3); f32x4 p3b = MFMA16(W2f13, B21, zero4);
        uint4 q30, q31;
        q30.x = pk2r(p0[0] + p0b[0], p0[1] + p0b[1]);
        q30.y = pk2r(p0[2] + p0b[2], p0[3] + p0b[3]);
        q30.z = pk2r(p2[0] + p2b[0], p2[1] + p2b[1]);
        q30.w = pk2r(p2[2] + p2b[2], p2[3] + p2b[3]);
        q31.x = pk2r(p1[0] + p1b[0], p1[1] + p1b[1]);
        q31.y = pk2r(p1[2] + p1b[2], p1[3] + p1b[3]);
        q31.z = pk2r(p3[0] + p3b[0], p3[1] + p3b[1]);
        q31.w = pk2r(p3[2] + p3b[2], p3[3] + p3b[3]);
        bf16x8 B30 = as_bf(q30), B31 = as_bf(q31);
        // L3: independent partials, merged into the returned kk
        f32x4 ka = MFMA16(W3f0, B30, b3f);
        f32x4 kb = MFMA16(W3f1, B31, zero4);
        __builtin_amdgcn_s_setprio(0);
        f32x4 kk;
        kk[0] = ka[0] + kb[0];
        kk[1] = ka[1] + kb[1];
        kk[2] = ka[2] + kb[2];
        kk[3] = ka[3] + kb[3];
        return kk;
    };

#pragma unroll 1
    for (int step = 0; step < 8; ++step) {
        float a0 = yv0, a1 = yv1, a2 = yv2, a3 = yv3;
        float c0 = 0.f, c1 = 0.f, c2 = 0.f, c3 = 0.f;
#pragma unroll 1
        for (int s = 0; s < 4; ++s) {
            f32x4 kk = rhs(a0, a1, a2, a3);
            float wk = (s == 1 || s == 2) ? 2.f : 1.f;
            float cs = (s < 2) ? 0.0625f : (s == 2) ? 0.125f : 0.f;
            c0 = fmaf(wk, kk[0], c0); c1 = fmaf(wk, kk[1], c1);
            c2 = fmaf(wk, kk[2], c2); c3 = fmaf(wk, kk[3], c3);
            a0 = fmaf(cs, kk[0], yv0); a1 = fmaf(cs, kk[1], yv1);
            a2 = fmaf(cs, kk[2], yv2); a3 = fmaf(cs, kk[3], yv3);
        }
        yv0 = fmaf(dt6, c0, yv0); yv1 = fmaf(dt6, c1, yv1);
        yv2 = fmaf(dt6, c2, yv2); yv3 = fmaf(dt6, c3, yv3);
    }

    *(float4*)(out + (size_t)edge * 16 + 4 * g) = make_float4(yv0, yv1, yv2, yv3);
}

extern "C" void kernel_launch(void* const* d_in, const int* in_sizes, int n_in,
                              void* d_out, int out_size, void* d_ws, size_t ws_size,
                              hipStream_t stream) {
    const float* x     = (const float*)d_in[0];
    const int*   ei    = (const int*)d_in[1];
    const float* ea    = (const float*)d_in[2];
    const float* Wg    = (const float*)d_in[3];
    const float* a_src = (const float*)d_in[4];
    const float* a_dst = (const float*)d_in[5];
    const float* b_gat = (const float*)d_in[6];
    const float* W1    = (const float*)d_in[7];
    const float* b1    = (const float*)d_in[8];
    const float* W2    = (const float*)d_in[9];
    const float* b2    = (const float*)d_in[10];
    const float* W3    = (const float*)d_in[11];
    const float* b3    = (const float*)d_in[12];

    float* ws  = (float*)d_ws;
    float* h   = ws + OFF_H;
    float* hs  = ws + OFF_HS;
    float* hd  = ws + OFF_HD;
    float* den = ws + OFF_DEN;
    float* xg  = ws + OFF_XG;
    uint32_t* img = (uint32_t*)(ws + OFF_IMG);

    prep_kernel<<<1, 64, 0, stream>>>(W1, b1, W2, b2, W3, b3, img);
    node_kernel<<<(NN + 255) / 256, 256, 0, stream>>>(x, Wg, a_src, a_dst,
                                                      h, hs, hd, den, xg);
    edge_kernel<<<NE / 512, 256, 0, stream>>>(ei, hs, hd, h, den, xg);
    div_kernel<<<(NN + 255) / 256, 256, 0, stream>>>(hs, hd, h, xg, den, b_gat);
    rk4_kernel<<<NE / 64, 256, 0, stream>>>(ei, ea, xg, img, (float*)d_out);
}

// Round 16
// 936.072 us; speedup vs baseline: 1.0813x; 1.0813x over previous
//
#include <hip/hip_runtime.h>
#include <math.h>
#include <stdint.h>

#define NN 100000
#define NE 1600000
#define IN_DIM 128
#define HID 64
#define EDIM 16
#define NEG_SLOPE 0.2f

// ws layout (float offsets)
#define OFF_H    0          // NN*4
#define OFF_HS   400000     // NN
#define OFF_HD   500000     // NN
#define OFF_DEN  600000     // NN
#define OFF_XG   700000     // NN*4
#define OFF_IMG  2800000    // 19*256 u32

typedef __attribute__((ext_vector_type(8))) short bf16x8;
typedef __attribute__((ext_vector_type(4))) float f32x4;
typedef __attribute__((ext_vector_type(2))) float f32x2;
typedef __attribute__((ext_vector_type(2))) __bf16 bf16x2;
typedef __attribute__((ext_vector_type(2))) short s16x2;

#define MFMA16(A, B, C) __builtin_amdgcn_mfma_f32_16x16x32_bf16((A), (B), (C), 0, 0, 0)

__device__ inline bf16x8 as_bf(uint4 x) { union { uint4 a; bf16x8 b; } u; u.a = x; return u.b; }
__device__ inline f32x4 as_f4(uint4 x) { union { uint4 a; f32x4 f; } u; u.a = x; return u.f; }

// packed f32x2 -> bf16x2 via LLVM fptrunc (validated r10; lowers to v_cvt_pk_bf16_f32)
__device__ inline uint32_t pk2(float lo, float hi) {
    f32x2 v; v.x = lo; v.y = hi;
    bf16x2 b = __builtin_convertvector(v, bf16x2);
    union { bf16x2 b; uint32_t u; } uu; uu.b = b; return uu.u;
}

// convert + packed relu (validated r12): bf16 sign-magnitude => smax(i16,0) == relu
__device__ inline uint32_t pk2r(float lo, float hi) {
    f32x2 v; v.x = lo; v.y = hi;
    bf16x2 b = __builtin_convertvector(v, bf16x2);
    union { bf16x2 b; s16x2 s; uint32_t u; } uu; uu.b = b;
    s16x2 z = {0, 0};
    uu.s = __builtin_elementwise_max(uu.s, z);
    return uu.u;
}

// prep-side RNE pack (cold path)
__device__ inline uint16_t f2bf_rne(float f) {
    uint32_t x = __float_as_uint(f);
    uint32_t r = x + 0x7FFFu + ((x >> 16) & 1u);
    return (uint16_t)(r >> 16);
}
__device__ inline uint32_t pk2c(float lo, float hi) {
    return (uint32_t)f2bf_rne(lo) | ((uint32_t)f2bf_rne(hi) << 16);
}

// ---------------- GAT conv (r15 form, validated) ----------------
__global__ void node_kernel(const float* __restrict__ x, const float* __restrict__ Wg,
                            const float* __restrict__ a_src, const float* __restrict__ a_dst,
                            float* __restrict__ h, float* __restrict__ hs,
                            float* __restrict__ hd, float* __restrict__ den,
                            float* __restrict__ xg) {
    int i = blockIdx.x * blockDim.x + threadIdx.x;
    if (i >= NN) return;
    float acc0 = 0.f, acc1 = 0.f, acc2 = 0.f, acc3 = 0.f;
    const float* xr = x + (size_t)i * IN_DIM;
#pragma unroll
    for (int d = 0; d < IN_DIM; d += 4) {
        float4 xv = *(const float4*)(xr + d);
        acc0 = fmaf(xv.x, Wg[(d + 0) * 4 + 0], acc0);
        acc1 = fmaf(xv.x, Wg[(d + 0) * 4 + 1], acc1);
        acc2 = fmaf(xv.x, Wg[(d + 0) * 4 + 2], acc2);
        acc3 = fmaf(xv.x, Wg[(d + 0) * 4 + 3], acc3);
        acc0 = fmaf(xv.y, Wg[(d + 1) * 4 + 0], acc0);
        acc1 = fmaf(xv.y, Wg[(d + 1) * 4 + 1], acc1);
        acc2 = fmaf(xv.y, Wg[(d + 1) * 4 + 2], acc2);
        acc3 = fmaf(xv.y, Wg[(d + 1) * 4 + 3], acc3);
        acc0 = fmaf(xv.z, Wg[(d + 2) * 4 + 0], acc0);
        acc1 = fmaf(xv.z, Wg[(d + 2) * 4 + 1], acc1);
        acc2 = fmaf(xv.z, Wg[(d + 2) * 4 + 2], acc2);
        acc3 = fmaf(xv.z, Wg[(d + 2) * 4 + 3], acc3);
        acc0 = fmaf(xv.w, Wg[(d + 3) * 4 + 0], acc0);
        acc1 = fmaf(xv.w, Wg[(d + 3) * 4 + 1], acc1);
        acc2 = fmaf(xv.w, Wg[(d + 3) * 4 + 2], acc2);
        acc3 = fmaf(xv.w, Wg[(d + 3) * 4 + 3], acc3);
    }
    *(float4*)(h + (size_t)i * 4) = make_float4(acc0, acc1, acc2, acc3);
    hs[i] = acc0 * a_src[0] + acc1 * a_src[1] + acc2 * a_src[2] + acc3 * a_src[3];
    hd[i] = acc0 * a_dst[0] + acc1 * a_dst[1] + acc2 * a_dst[2] + acc3 * a_dst[3];
    den[i] = 0.f;
    *(float4*)(xg + (size_t)i * 4) = make_float4(0.f, 0.f, 0.f, 0.f);
}

// real edges, 2 per thread (int2 coalesced index loads); self-loops in div_kernel
__global__ __launch_bounds__(256) void edge_kernel(
    const int* __restrict__ ei, const float* __restrict__ hs,
    const float* __restrict__ hd, const float* __restrict__ h,
    float* __restrict__ den, float* __restrict__ xg) {
    int t = blockIdx.x * blockDim.x + threadIdx.x;
    int e = 2 * t;
    if (e >= NE) return;
    int2 rr = *(const int2*)(ei + e);
    int2 cc = *(const int2*)(ei + NE + e);
    float v0 = hs[rr.x] + hd[cc.x];
    float v1 = hs[rr.y] + hd[cc.y];
    v0 = (v0 >= 0.f) ? v0 : NEG_SLOPE * v0;
    v1 = (v1 >= 0.f) ? v1 : NEG_SLOPE * v1;
    float p0 = __expf(v0), p1 = __expf(v1);
    float4 h0 = *(const float4*)(h + (size_t)rr.x * 4);
    float4 h1 = *(const float4*)(h + (size_t)rr.y * 4);
    atomicAdd(&den[cc.x], p0);
    atomicAdd(&xg[4 * cc.x + 0], p0 * h0.x);
    atomicAdd(&xg[4 * cc.x + 1], p0 * h0.y);
    atomicAdd(&xg[4 * cc.x + 2], p0 * h0.z);
    atomicAdd(&xg[4 * cc.x + 3], p0 * h0.w);
    atomicAdd(&den[cc.y], p1);
    atomicAdd(&xg[4 * cc.y + 0], p1 * h1.x);
    atomicAdd(&xg[4 * cc.y + 1], p1 * h1.y);
    atomicAdd(&xg[4 * cc.y + 2], p1 * h1.z);
    atomicAdd(&xg[4 * cc.y + 3], p1 * h1.w);
}

// self-loop contribution + normalization + bias
__global__ void div_kernel(const float* __restrict__ hs, const float* __restrict__ hd,
                           const float* __restrict__ h, float* __restrict__ xg,
                           const float* __restrict__ den, const float* __restrict__ b_gat) {
    int i = blockIdx.x * blockDim.x + threadIdx.x;
    if (i >= NN) return;
    float v = hs[i] + hd[i];
    v = (v >= 0.f) ? v : NEG_SLOPE * v;
    float pe = __expf(v);
    float4 hv = *(const float4*)(h + (size_t)i * 4);
    float inv = 1.0f / (den[i] + pe);
    float4 n = *(const float4*)(xg + (size_t)i * 4);
    *(float4*)(xg + (size_t)i * 4) =
        make_float4(fmaf(fmaf(pe, hv.x, n.x), inv, b_gat[0]),
                    fmaf(fmaf(pe, hv.y, n.y), inv, b_gat[1]),
                    fmaf(fmaf(pe, hv.z, n.z), inv, b_gat[2]),
                    fmaf(fmaf(pe, hv.w, n.w), inv, b_gat[3]));
}

// ---------------- fragment image prep (PERMUTED layout, validated r8-r15) ----------------
// u(q,g,r) = 32*(q&1) + 8*g + 4*(q>>1) + r; D-slot order == next layer's B k-order.
// Layer-1 B per lane g: j=0..3 -> y[4g+j]; j=4,5 -> f[2g],f[2g+1];
// j=6 (g==0 only) -> bias-one; j=7 -> zero.
__global__ void prep_kernel(const float* __restrict__ W1, const float* __restrict__ b1,
                            const float* __restrict__ W2, const float* __restrict__ b2,
                            const float* __restrict__ W3, const float* __restrict__ b3,
                            uint32_t* __restrict__ img) {
    int l = threadIdx.x;
    if (l >= 64) return;
    int e = l & 15, g = l >> 4;
    int er = e & 3, eq = e >> 2;
    for (int q = 0; q < 4; ++q) {
        int u = 32 * (q & 1) + 8 * eq + 4 * (q >> 1) + er;
        img[q * 256 + l * 4 + 0] = pk2c(W1[(8 + 4 * g + 0) * 64 + u], W1[(8 + 4 * g + 1) * 64 + u]);
        img[q * 256 + l * 4 + 1] = pk2c(W1[(8 + 4 * g + 2) * 64 + u], W1[(8 + 4 * g + 3) * 64 + u]);
        img[q * 256 + l * 4 + 2] = pk2c(W1[(2 * g + 0) * 64 + u], W1[(2 * g + 1) * 64 + u]);
        img[q * 256 + l * 4 + 3] = pk2c((g == 0) ? b1[u] : 0.f, 0.f);
    }
    for (int t = 0; t < 2; ++t)
        for (int q = 0; q < 4; ++q) {
            int u = 32 * (q & 1) + 8 * eq + 4 * (q >> 1) + er;
            for (int j2 = 0; j2 < 4; ++j2) {
                int k0 = 32 * t + 8 * g + 2 * j2;
                img[(4 + t * 4 + q) * 256 + l * 4 + j2] =
                    pk2c(W2[k0 * 64 + u], W2[(k0 + 1) * 64 + u]);
            }
        }
    for (int t = 0; t < 2; ++t)
        for (int j2 = 0; j2 < 4; ++j2) {
            int k0 = 32 * t + 8 * g + 2 * j2;
            img[(12 + t) * 256 + l * 4 + j2] =
                pk2c(W3[k0 * 16 + e], W3[(k0 + 1) * 16 + e]);
        }
    for (int q = 0; q < 4; ++q)
        for (int r = 0; r < 4; ++r)
            img[(14 + q) * 256 + l * 4 + r] =
                __float_as_uint(b2[32 * (q & 1) + 8 * g + 4 * (q >> 1) + r]);
    for (int r = 0; r < 4; ++r)
        img[18 * 256 + l * 4 + r] = __float_as_uint(b3[4 * g + r]);
}

// ---------------- RK4 edge MLP (r16 = r14 validated form, best: 567us) ----------------
__global__ __launch_bounds__(256, 4) void rk4_kernel(
    const int* __restrict__ ei, const float* __restrict__ ea,
    const float* __restrict__ xg, const uint32_t* __restrict__ img,
    float* __restrict__ out) {
    const int tid = threadIdx.x;
    const int w = tid >> 6, l = tid & 63;
    const int e = l & 15, g = l >> 4;
    const int edge = blockIdx.x * 64 + w * 16 + e;

    uint4 F[19];
#pragma unroll
    for (int i = 0; i < 19; ++i) F[i] = *(const uint4*)(img + i * 256 + l * 4);

    const bf16x8 W1f0 = as_bf(F[0]), W1f1 = as_bf(F[1]), W1f2 = as_bf(F[2]), W1f3 = as_bf(F[3]);
    const bf16x8 W2f00 = as_bf(F[4]), W2f01 = as_bf(F[5]), W2f02 = as_bf(F[6]), W2f03 = as_bf(F[7]);
    const bf16x8 W2f10 = as_bf(F[8]), W2f11 = as_bf(F[9]), W2f12 = as_bf(F[10]), W2f13 = as_bf(F[11]);
    const bf16x8 W3f0 = as_bf(F[12]), W3f1 = as_bf(F[13]);
    const f32x4 b2f0 = as_f4(F[14]), b2f1 = as_f4(F[15]), b2f2 = as_f4(F[16]), b2f3 = as_f4(F[17]);
    const f32x4 b3f = as_f4(F[18]);

    uint32_t Stf, Stb;
    {
        int idx = (g < 2) ? ei[edge] : ei[NE + edge];
        const float2 fv = *(const float2*)(xg + (size_t)idx * 4 + ((2 * g) & 3));
        Stf = pk2(fv.x, fv.y);
        Stb = (g == 0) ? 0x00003F80u : 0u;  // bf16(1.0) at k=6
    }

    float4 y4 = *(const float4*)(ea + (size_t)edge * 16 + 4 * g);
    float yv0 = y4.x, yv1 = y4.y, yv2 = y4.z, yv3 = y4.w;

    const f32x4 zero4 = {0.f, 0.f, 0.f, 0.f};
    const float dt6 = 0.125f / 6.0f;

    auto rhs = [&](float a0, float a1, float a2, float a3) -> f32x4 {
        uint4 bb;
        bb.x = pk2(a0, a1); bb.y = pk2(a2, a3); bb.z = Stf; bb.w = Stb;
        bf16x8 B1 = as_bf(bb);
        __builtin_amdgcn_s_setprio(1);
        f32x4 h0 = MFMA16(W1f0, B1, zero4);
        f32x4 h1 = MFMA16(W1f1, B1, zero4);
        f32x4 h2 = MFMA16(W1f2, B1, zero4);
        f32x4 h3 = MFMA16(W1f3, B1, zero4);
        uint4 q20, q21;
        q20.x = pk2r(h0[0], h0[1]);
        q20.y = pk2r(h0[2], h0[3]);
        q20.z = pk2r(h2[0], h2[1]);
        q20.w = pk2r(h2[2], h2[3]);
        q21.x = pk2r(h1[0], h1[1]);
        q21.y = pk2r(h1[2], h1[3]);
        q21.z = pk2r(h3[0], h3[1]);
        q21.w = pk2r(h3[2], h3[3]);
        bf16x8 B20 = as_bf(q20), B21 = as_bf(q21);
        f32x4 p0 = MFMA16(W2f00, B20, b2f0); p0 = MFMA16(W2f10, B21, p0);
        f32x4 p1 = MFMA16(W2f01, B20, b2f1); p1 = MFMA16(W2f11, B21, p1);
        f32x4 p2 = MFMA16(W2f02, B20, b2f2); p2 = MFMA16(W2f12, B21, p2);
        f32x4 p3 = MFMA16(W2f03, B20, b2f3); p3 = MFMA16(W2f13, B21, p3);
        uint4 q30, q31;
        q30.x = pk2r(p0[0], p0[1]);
        q30.y = pk2r(p0[2], p0[3]);
        q30.z = pk2r(p2[0], p2[1]);
        q30.w = pk2r(p2[2], p2[3]);
        q31.x = pk2r(p1[0], p1[1]);
        q31.y = pk2r(p1[2], p1[3]);
        q31.z = pk2r(p3[0], p3[1]);
        q31.w = pk2r(p3[2], p3[3]);
        bf16x8 B30 = as_bf(q30), B31 = as_bf(q31);
        f32x4 kk = MFMA16(W3f0, B30, b3f);
        kk = MFMA16(W3f1, B31, kk);
        __builtin_amdgcn_s_setprio(0);
        return kk;
    };

#pragma unroll 1
    for (int step = 0; step < 8; ++step) {
        float a0 = yv0, a1 = yv1, a2 = yv2, a3 = yv3;
        float c0 = 0.f, c1 = 0.f, c2 = 0.f, c3 = 0.f;
#pragma unroll 1
        for (int s = 0; s < 4; ++s) {
            f32x4 kk = rhs(a0, a1, a2, a3);
            float wk = (s == 1 || s == 2) ? 2.f : 1.f;
            float cs = (s < 2) ? 0.0625f : (s == 2) ? 0.125f : 0.f;
            c0 = fmaf(wk, kk[0], c0); c1 = fmaf(wk, kk[1], c1);
            c2 = fmaf(wk, kk[2], c2); c3 = fmaf(wk, kk[3], c3);
            a0 = fmaf(cs, kk[0], yv0); a1 = fmaf(cs, kk[1], yv1);
            a2 = fmaf(cs, kk[2], yv2); a3 = fmaf(cs, kk[3], yv3);
        }
        yv0 = fmaf(dt6, c0, yv0); yv1 = fmaf(dt6, c1, yv1);
        yv2 = fmaf(dt6, c2, yv2); yv3 = fmaf(dt6, c3, yv3);
    }

    *(float4*)(out + (size_t)edge * 16 + 4 * g) = make_float4(yv0, yv1, yv2, yv3);
}

extern "C" void kernel_launch(void* const* d_in, const int* in_sizes, int n_in,
                              void* d_out, int out_size, void* d_ws, size_t ws_size,
                              hipStream_t stream) {
    const float* x     = (const float*)d_in[0];
    const int*   ei    = (const int*)d_in[1];
    const float* ea    = (const float*)d_in[2];
    const float* Wg    = (const float*)d_in[3];
    const float* a_src = (const float*)d_in[4];
    const float* a_dst = (const float*)d_in[5];
    const float* b_gat = (const float*)d_in[6];
    const float* W1    = (const float*)d_in[7];
    const float* b1    = (const float*)d_in[8];
    const float* W2    = (const float*)d_in[9];
    const float* b2    = (const float*)d_in[10];
    const float* W3    = (const float*)d_in[11];
    const float* b3    = (const float*)d_in[12];

    float* ws  = (float*)d_ws;
    float* h   = ws + OFF_H;
    float* hs  = ws + OFF_HS;
    float* hd  = ws + OFF_HD;
    float* den = ws + OFF_DEN;
    float* xg  = ws + OFF_XG;
    uint32_t* img = (uint32_t*)(ws + OFF_IMG);

    prep_kernel<<<1, 64, 0, stream>>>(W1, b1, W2, b2, W3, b3, img);
    node_kernel<<<(NN + 255) / 256, 256, 0, stream>>>(x, Wg, a_src, a_dst,
                                                      h, hs, hd, den, xg);
    edge_kernel<<<NE / 512, 256, 0, stream>>>(ei, hs, hd, h, den, xg);
    div_kernel<<<(NN + 255) / 256, 256, 0, stream>>>(hs, hd, h, xg, den, b_gat);
    rk4_kernel<<<NE / 64, 256, 0, stream>>>(ei, ea, xg, img, (float*)d_out);
}